// Round 16
// baseline (551.159 us; speedup 1.0000x reference)
//
#include <hip/hip_runtime.h>
#include <hip/hip_fp16.h>

#define NN 40000
#define NE 640000
#define HID 128
#define NL 5
#define NBLK 157  // ceil(40000/256)
#define LSTRIDE 136  // 128 + 8 pad shorts -> 272B rows; 2-way bank aliasing only (free)

typedef __attribute__((ext_vector_type(8))) short bf16x8;
typedef __attribute__((ext_vector_type(4))) float f32x4;

static __device__ __forceinline__ unsigned short f32_to_bf16_rne(float f) {
  unsigned int u = __float_as_uint(f);
  unsigned int lsb = (u >> 16) & 1u;
  u += 0x7fffu + lsb;
  return (unsigned short)(u >> 16);
}
static __device__ __forceinline__ float bf16_to_f32(unsigned short s) {
  return __uint_as_float(((unsigned int)s) << 16);
}

// ---- fused: encoder (blocks 0..19999) + conv_W bf16 hi/lo split (blocks 20000+) ----
__global__ void encoder_wconv_kernel(const float* __restrict__ x, const float* __restrict__ encW,
                                     const float* __restrict__ encb, __half* __restrict__ h,
                                     const float* __restrict__ convW,
                                     unsigned short* __restrict__ whi,
                                     unsigned short* __restrict__ wlo) {
  int b = blockIdx.x;
  if (b < 20000) {
    int gid = b * 256 + threadIdx.x;  // < NN*HID
    int n = gid >> 7, k = gid & 127;
    const float* xp = x + n * 7;
    const float* wp = encW + k * 7;
    float acc = encb[k];
#pragma unroll
    for (int i = 0; i < 7; ++i) acc += xp[i] * wp[i];
    h[gid] = __float2half(acc);
  } else {
    int i = (b - 20000) * 256 + threadIdx.x;
    if (i < NL * HID * HID) {
      float w = convW[i];
      unsigned short hi = f32_to_bf16_rne(w);
      unsigned short lo = f32_to_bf16_rne(w - bf16_to_f32(hi));
      whi[i] = hi;
      wlo[i] = lo;
    }
  }
}

// ---------------- CSR build ----------------
__global__ void hist_kernel(const int* __restrict__ dst, int* __restrict__ cnt,
                            int* __restrict__ rank) {
  int e = blockIdx.x * blockDim.x + threadIdx.x;
  if (e < NE) rank[e] = atomicAdd(&cnt[dst[e]], 1);
}

__global__ void partial_kernel(const int* __restrict__ cnt, int* __restrict__ blocksum) {
  __shared__ int red[4];
  int t = threadIdx.x;
  int idx = blockIdx.x * 256 + t;
  int v = idx < NN ? cnt[idx] : 0;
#pragma unroll
  for (int off = 32; off > 0; off >>= 1) v += __shfl_xor(v, off, 64);
  if ((t & 63) == 0) red[t >> 6] = v;
  __syncthreads();
  if (t == 0) blocksum[blockIdx.x] = red[0] + red[1] + red[2] + red[3];
}

__global__ void scan_small_kernel(const int* __restrict__ blocksum, int* __restrict__ blockoff,
                                  int* __restrict__ row_ptr) {
  __shared__ int sh[256];
  int t = threadIdx.x;
  int v = t < NBLK ? blocksum[t] : 0;
  sh[t] = v;
  __syncthreads();
  for (int off = 1; off < 256; off <<= 1) {
    int u = (t >= off) ? sh[t - off] : 0;
    __syncthreads();
    sh[t] += u;
    __syncthreads();
  }
  if (t < NBLK) blockoff[t] = sh[t] - v;
  if (t == 255) row_ptr[NN] = sh[255];
}

__global__ void rowptr_kernel(const int* __restrict__ cnt, const int* __restrict__ blockoff,
                              int* __restrict__ row_ptr) {
  __shared__ int sh[256];
  int t = threadIdx.x;
  int idx = blockIdx.x * 256 + t;
  int v = idx < NN ? cnt[idx] : 0;
  sh[t] = v;
  __syncthreads();
  for (int off = 1; off < 256; off <<= 1) {
    int u = (t >= off) ? sh[t - off] : 0;
    __syncthreads();
    sh[t] += u;
    __syncthreads();
  }
  if (idx < NN) row_ptr[idx] = blockoff[blockIdx.x] + sh[t] - v;
}

// ---- degree-sorted node permutation (counting sort, 256 bins) ----
// Only changes WHICH block processes which node -> per-node math and output
// location unchanged; atomic ordering inside a bin does not affect results.
__global__ void dhist_kernel(const int* __restrict__ cnt, int* __restrict__ dbin) {
  int n = blockIdx.x * 256 + threadIdx.x;
  if (n < NN) {
    int d = cnt[n];
    if (d > 255) d = 255;
    atomicAdd(&dbin[d], 1);
  }
}

__global__ void dscan_kernel(const int* __restrict__ dbin, int* __restrict__ doff) {
  __shared__ int sh[256];
  int t = threadIdx.x;
  int v = dbin[t];
  sh[t] = v;
  __syncthreads();
  for (int off = 1; off < 256; off <<= 1) {
    int u = (t >= off) ? sh[t - off] : 0;
    __syncthreads();
    sh[t] += u;
    __syncthreads();
  }
  doff[t] = sh[t] - v;  // exclusive
}

__global__ void dperm_kernel(const int* __restrict__ cnt, const int* __restrict__ doff,
                             int* __restrict__ dfill, int* __restrict__ perm) {
  int n = blockIdx.x * 256 + threadIdx.x;
  if (n < NN) {
    int d = cnt[n];
    if (d > 255) d = 255;
    int pos = doff[d] + atomicAdd(&dfill[d], 1);
    perm[pos] = n;
  }
}

// pure read + ONE 8B store per edge (no atomic: rank precomputed in hist).
__global__ void scatter_kernel(const int* __restrict__ src, const int* __restrict__ dst,
                               const float* __restrict__ dist,
                               const int* __restrict__ row_ptr, const int* __restrict__ rank,
                               int2* __restrict__ csr_ew) {
  int e = blockIdx.x * blockDim.x + threadIdx.x;
  if (e >= NE) return;
  int pos = row_ptr[dst[e]] + rank[e];
  float dd = dist[e] + 1e-6f;
  float w = 1.0f / (dd * dd);
  csr_ew[pos] = make_int2(src[e], (int)__float_as_uint(w));
}

__global__ void wsum_kernel(const int* __restrict__ row_ptr, const int2* __restrict__ csr_ew,
                            float* __restrict__ wsum) {
  int n = blockIdx.x * blockDim.x + threadIdx.x;
  if (n >= NN) return;
  int s = row_ptr[n], e = row_ptr[n + 1];
  float acc = 0.f;
  for (int i = s; i < e; ++i) acc += __uint_as_float((unsigned)csr_ew[i].y);
  wsum[n] = acc;
}

// -------- fused per-layer: wave-per-node gather -> LDS -> MFMA linear -> hout --------
// Block = 16 waves = 16 degree-sorted nodes (perm) -> all waves have ~equal edge
// counts -> minimal __syncthreads imbalance. Phase 1: each wave runs the 4-edge/
// VMEM gather for ITS node, writes bf16 hi/lo row to LDS. One barrier. Phase 2:
// waves 0-7 each compute one 16x16 output tile from the shared LDS A-tile via
// split-bf16 MFMA (a*w ~= ah*wh + ah*wl + al*wh, fp32 acc), store to natural rows.
// D-layout: col(kout)=lane&15, row(slot)=(lane>>4)*4+reg [guide §3, m89-verified].
// hin/hout double-buffered (blocks read random hin rows while others write hout).
__global__ void __launch_bounds__(1024) fused_layer_kernel(
    const __half* __restrict__ hin, const int* __restrict__ row_ptr,
    const int2* __restrict__ csr_ew, const int* __restrict__ perm,
    const unsigned short* __restrict__ whi, const unsigned short* __restrict__ wlo,
    const float* __restrict__ wsum, const float* __restrict__ b,
    __half* __restrict__ hout) {
  __shared__ __align__(16) unsigned short sAh[16][LSTRIDE];
  __shared__ __align__(16) unsigned short sAl[16][LSTRIDE];
  int wave = threadIdx.x >> 6;
  int lane = threadIdx.x & 63;
  int wid = __builtin_amdgcn_readfirstlane(perm[blockIdx.x * 16 + wave]);  // this wave's node

  // ---- phase 1: aggregate this wave's node (4 edges per VMEM instr) ----
  {
    int s = __builtin_amdgcn_readfirstlane(row_ptr[wid]);
    int e = __builtin_amdgcn_readfirstlane(row_ptr[wid + 1]);
    int g = lane >> 4;   // edge slot within a quad
    int k = lane & 15;   // col octet: cols [8k, 8k+8)
    const __half* hp = hin + k * 8;
    float a[8] = {0.f, 0.f, 0.f, 0.f, 0.f, 0.f, 0.f, 0.f};
    int i = s;
    for (; i + 16 <= e; i += 16) {  // clamp-free main strips
      uint4 hv[4];
      float wv[4];
#pragma unroll
      for (int u = 0; u < 4; ++u) {
        int2 p = csr_ew[i + u * 4 + g];
        wv[u] = __uint_as_float((unsigned)p.y);
        hv[u] = *reinterpret_cast<const uint4*>(hp + (size_t)p.x * HID);
      }
#pragma unroll
      for (int u = 0; u < 4; ++u) {
        const __half2* q = reinterpret_cast<const __half2*>(&hv[u]);
#pragma unroll
        for (int c = 0; c < 4; ++c) {
          float2 f = __half22float2(q[c]);
          a[2 * c] += wv[u] * f.x;
          a[2 * c + 1] += wv[u] * f.y;
        }
      }
    }
    for (; i < e; i += 4) {  // tail quads (clamped, w=0 pads vanish exactly)
      int j = i + g;
      int jc = j < e ? j : e - 1;
      int2 p = csr_ew[jc];
      float w = (j < e) ? __uint_as_float((unsigned)p.y) : 0.f;
      uint4 hv = *reinterpret_cast<const uint4*>(hp + (size_t)p.x * HID);
      const __half2* q = reinterpret_cast<const __half2*>(&hv);
#pragma unroll
      for (int c = 0; c < 4; ++c) {
        float2 f = __half22float2(q[c]);
        a[2 * c] += w * f.x;
        a[2 * c + 1] += w * f.y;
      }
    }
#pragma unroll
    for (int c = 0; c < 8; ++c) {
      a[c] += __shfl_xor(a[c], 16, 64);
      a[c] += __shfl_xor(a[c], 32, 64);
    }
    if (g == 0) {
      unsigned short hh[8], ll[8];
#pragma unroll
      for (int c = 0; c < 8; ++c) {
        hh[c] = f32_to_bf16_rne(a[c]);
        ll[c] = f32_to_bf16_rne(a[c] - bf16_to_f32(hh[c]));
      }
      *reinterpret_cast<uint4*>(&sAh[wave][k * 8]) = *reinterpret_cast<const uint4*>(hh);
      *reinterpret_cast<uint4*>(&sAl[wave][k * 8]) = *reinterpret_cast<const uint4*>(ll);
    }
  }
  __syncthreads();

  // ---- phase 2: waves 0-7 each compute one 16x16 output tile ----
  if (wave >= 8) return;
  int t = wave;
  int mrow = lane & 15;
  int kc = (lane >> 4) * 8;

  f32x4 acc = (f32x4){0.f, 0.f, 0.f, 0.f};
#pragma unroll
  for (int si = 0; si < 4; ++si) {
    int joff = si * 32 + kc;
    bf16x8 ah = *reinterpret_cast<const bf16x8*>(&sAh[mrow][joff]);
    bf16x8 al = *reinterpret_cast<const bf16x8*>(&sAl[mrow][joff]);
    bf16x8 bh = *reinterpret_cast<const bf16x8*>(whi + (t * 16 + mrow) * HID + joff);
    bf16x8 bl = *reinterpret_cast<const bf16x8*>(wlo + (t * 16 + mrow) * HID + joff);
    acc = __builtin_amdgcn_mfma_f32_16x16x32_bf16(ah, bh, acc, 0, 0, 0);
    acc = __builtin_amdgcn_mfma_f32_16x16x32_bf16(ah, bl, acc, 0, 0, 0);
    acc = __builtin_amdgcn_mfma_f32_16x16x32_bf16(al, bh, acc, 0, 0, 0);
  }

  int slotBase = (lane >> 4) * 4;
  int kout = t * 16 + mrow;
  float bk = b[kout];
#pragma unroll
  for (int r = 0; r < 4; ++r) {
    int node = perm[blockIdx.x * 16 + slotBase + r];
    float v = acc[r] + bk * wsum[node];
    hout[(size_t)node * HID + kout] = __float2half(fmaxf(v, 0.f));
  }
}

// ---------------- cluster softmax head (wave per node) ----------------
__global__ void cluster_kernel(const __half* __restrict__ h, const float* __restrict__ cW,
                               const float* __restrict__ cb, float* __restrict__ out) {
  int wid = (blockIdx.x * blockDim.x + threadIdx.x) >> 6;
  int lane = threadIdx.x & 63;
  if (wid >= NN) return;
  float h0 = __half2float(h[wid * HID + lane]);
  float h1 = __half2float(h[wid * HID + 64 + lane]);
  float logit[3];
#pragma unroll
  for (int c = 0; c < 3; ++c) {
    float p = h0 * cW[c * HID + lane] + h1 * cW[c * HID + 64 + lane];
#pragma unroll
    for (int off = 32; off > 0; off >>= 1) p += __shfl_xor(p, off, 64);
    logit[c] = p + cb[c];
  }
  if (lane == 0) {
    float m = fmaxf(logit[0], fmaxf(logit[1], logit[2]));
    float e0 = expf(logit[0] - m), e1 = expf(logit[1] - m), e2 = expf(logit[2] - m);
    float inv = 1.0f / (e0 + e1 + e2);
    out[wid * 3 + 0] = e0 * inv;
    out[wid * 3 + 1] = e1 * inv;
    out[wid * 3 + 2] = e2 * inv;
  }
}

// ---------------- energy head: two-stage column reduction ----------------
__global__ void colsum_part_kernel(const __half* __restrict__ h, float* __restrict__ partial) {
  int t = threadIdx.x;
  int col = t & 127;
  int lane_id = blockIdx.x * 2 + (t >> 7);  // [0, 2048)
  float acc = 0.f;
  for (int r = lane_id; r < NN; r += 2048) acc += __half2float(h[r * HID + col]);
  partial[lane_id * HID + col] = acc;
}

__global__ void energy_final_kernel(const float* __restrict__ partial,
                                    const float* __restrict__ eW, const float* __restrict__ eb,
                                    float* __restrict__ out) {
  __shared__ float sh[8][HID];
  __shared__ float red[2];
  int t = threadIdx.x;
  int col = t & 127;
  int slot = t >> 7;  // 0..7
  float acc = 0.f;
  for (int i = 0; i < 256; ++i) acc += partial[(slot + 8 * i) * HID + col];
  sh[slot][col] = acc;
  __syncthreads();
  if (t < 128) {
    float s = 0.f;
#pragma unroll
    for (int j = 0; j < 8; ++j) s += sh[j][t];
    float v = s * (1.0f / NN) * eW[t];
#pragma unroll
    for (int off = 32; off > 0; off >>= 1) v += __shfl_xor(v, off, 64);
    if ((t & 63) == 0) red[t >> 6] = v;
  }
  __syncthreads();
  if (t == 0) {
    float e = red[0] + red[1] + eb[0];
    out[NN * 3] = e;
    out[NN * 3 + 1] = (e < -1.0f) ? 1.0f : 0.0f;
  }
}

extern "C" void kernel_launch(void* const* d_in, const int* in_sizes, int n_in,
                              void* d_out, int out_size, void* d_ws, size_t ws_size,
                              hipStream_t stream) {
  const float* x    = (const float*)d_in[0];
  const int*   ei   = (const int*)d_in[1];
  const float* dist = (const float*)d_in[2];
  const float* encW = (const float*)d_in[3];
  const float* encb = (const float*)d_in[4];
  const float* convW = (const float*)d_in[5];
  const float* convb = (const float*)d_in[6];
  const float* cW   = (const float*)d_in[7];
  const float* cb   = (const float*)d_in[8];
  const float* eW   = (const float*)d_in[9];
  const float* eb   = (const float*)d_in[10];
  float* out = (float*)d_out;

  // workspace layout (bytes)
  char* ws = (char*)d_ws;
  __half*         h1      = (__half*)        (ws + 0);           // 10,240,000
  __half*         h2      = (__half*)        (ws + 10240000);    // 10,240,000 (dbuf)
  char*           scratch = (char*)          (ws + 20480000);    // 10,240,000 (scan+bins+colsum)
  int2*           csr_ew  = (int2*)          (ws + 30720000);    //  5,120,000
  int*            row_ptr = (int*)           (ws + 35840000);    //    160,064
  int*            cnt     = (int*)           (ws + 36000064);    //    160,000
  float*          wsum    = (float*)         (ws + 36160064);    //    160,000
  unsigned short* whi5    = (unsigned short*)(ws + 36320064);    //    163,840
  unsigned short* wlo5    = (unsigned short*)(ws + 36483904);    //    163,840
  int*            rank    = (int*)           (ws + 36647744);    //  2,560,000
  int*            perm    = (int*)           (ws + 39207744);    //    160,000
  if (ws_size < (size_t)39367744) return;  // insufficient scratch — fail visibly

  int*   blocksum = (int*)scratch;            // 157 ints
  int*   blockoff = (int*)scratch + 512;      // 157 ints
  int*   dbin     = (int*)scratch + 1024;     // 256 ints
  int*   dfill    = (int*)scratch + 1280;     // 256 ints
  int*   doff     = (int*)scratch + 1536;     // 256 ints
  float* partial  = (float*)scratch;          // 1 MB (used after CSR build)

  const int* srcI = ei;
  const int* dstI = ei + NE;

  hipMemsetAsync(cnt, 0, 160000, stream);
  hipMemsetAsync(dbin, 0, 2048, stream);  // dbin + dfill (contiguous)

  encoder_wconv_kernel<<<20320, 256, 0, stream>>>(x, encW, encb, h1, convW, whi5, wlo5);

  hist_kernel<<<(NE + 255) / 256, 256, 0, stream>>>(dstI, cnt, rank);
  partial_kernel<<<NBLK, 256, 0, stream>>>(cnt, blocksum);
  scan_small_kernel<<<1, 256, 0, stream>>>(blocksum, blockoff, row_ptr);
  rowptr_kernel<<<NBLK, 256, 0, stream>>>(cnt, blockoff, row_ptr);
  dhist_kernel<<<NBLK, 256, 0, stream>>>(cnt, dbin);
  dscan_kernel<<<1, 256, 0, stream>>>(dbin, doff);
  dperm_kernel<<<NBLK, 256, 0, stream>>>(cnt, doff, dfill, perm);
  scatter_kernel<<<(NE + 255) / 256, 256, 0, stream>>>(srcI, dstI, dist, row_ptr, rank, csr_ew);
  wsum_kernel<<<(NN + 255) / 256, 256, 0, stream>>>(row_ptr, csr_ew, wsum);

  __half* hin = h1;
  __half* hout = h2;
  for (int l = 0; l < NL; ++l) {
    fused_layer_kernel<<<NN / 16, 1024, 0, stream>>>(hin, row_ptr, csr_ew, perm,
                                                     whi5 + (size_t)l * HID * HID,
                                                     wlo5 + (size_t)l * HID * HID,
                                                     wsum, convb + (size_t)l * HID, hout);
    __half* tmp = hin; hin = hout; hout = tmp;
  }
  // after 5 layers, final h is in hin

  cluster_kernel<<<(NN * 64 + 255) / 256, 256, 0, stream>>>(hin, cW, cb, out);
  colsum_part_kernel<<<1024, 256, 0, stream>>>(hin, partial);
  energy_final_kernel<<<1, 1024, 0, stream>>>(partial, eW, eb, out);
}

// Round 17
// 345.026 us; speedup vs baseline: 1.5974x; 1.5974x over previous
//
#include <hip/hip_runtime.h>
#include <hip/hip_fp16.h>

#define NN 40000
#define NE 640000
#define HID 128
#define NL 5
#define NBLK 157  // ceil(40000/256)
#define LSTRIDE 136  // 128 + 8 pad shorts -> 272B rows; 2-way bank aliasing only (free)

typedef __attribute__((ext_vector_type(8))) short bf16x8;
typedef __attribute__((ext_vector_type(4))) float f32x4;

static __device__ __forceinline__ unsigned short f32_to_bf16_rne(float f) {
  unsigned int u = __float_as_uint(f);
  unsigned int lsb = (u >> 16) & 1u;
  u += 0x7fffu + lsb;
  return (unsigned short)(u >> 16);
}
static __device__ __forceinline__ float bf16_to_f32(unsigned short s) {
  return __uint_as_float(((unsigned int)s) << 16);
}

// ---- fused: encoder (blocks 0..19999) + conv_W bf16 hi/lo split (blocks 20000+) ----
__global__ void encoder_wconv_kernel(const float* __restrict__ x, const float* __restrict__ encW,
                                     const float* __restrict__ encb, __half* __restrict__ h,
                                     const float* __restrict__ convW,
                                     unsigned short* __restrict__ whi,
                                     unsigned short* __restrict__ wlo) {
  int b = blockIdx.x;
  if (b < 20000) {
    int gid = b * 256 + threadIdx.x;  // < NN*HID
    int n = gid >> 7, k = gid & 127;
    const float* xp = x + n * 7;
    const float* wp = encW + k * 7;
    float acc = encb[k];
#pragma unroll
    for (int i = 0; i < 7; ++i) acc += xp[i] * wp[i];
    h[gid] = __float2half(acc);
  } else {
    int i = (b - 20000) * 256 + threadIdx.x;
    if (i < NL * HID * HID) {
      float w = convW[i];
      unsigned short hi = f32_to_bf16_rne(w);
      unsigned short lo = f32_to_bf16_rne(w - bf16_to_f32(hi));
      whi[i] = hi;
      wlo[i] = lo;
    }
  }
}

// ---------------- CSR build ----------------
__global__ void hist_kernel(const int* __restrict__ dst, int* __restrict__ cnt,
                            int* __restrict__ rank) {
  int e = blockIdx.x * blockDim.x + threadIdx.x;
  if (e < NE) rank[e] = atomicAdd(&cnt[dst[e]], 1);
}

__global__ void partial_kernel(const int* __restrict__ cnt, int* __restrict__ blocksum) {
  __shared__ int red[4];
  int t = threadIdx.x;
  int idx = blockIdx.x * 256 + t;
  int v = idx < NN ? cnt[idx] : 0;
#pragma unroll
  for (int off = 32; off > 0; off >>= 1) v += __shfl_xor(v, off, 64);
  if ((t & 63) == 0) red[t >> 6] = v;
  __syncthreads();
  if (t == 0) blocksum[blockIdx.x] = red[0] + red[1] + red[2] + red[3];
}

__global__ void scan_small_kernel(const int* __restrict__ blocksum, int* __restrict__ blockoff,
                                  int* __restrict__ row_ptr) {
  __shared__ int sh[256];
  int t = threadIdx.x;
  int v = t < NBLK ? blocksum[t] : 0;
  sh[t] = v;
  __syncthreads();
  for (int off = 1; off < 256; off <<= 1) {
    int u = (t >= off) ? sh[t - off] : 0;
    __syncthreads();
    sh[t] += u;
    __syncthreads();
  }
  if (t < NBLK) blockoff[t] = sh[t] - v;
  if (t == 255) row_ptr[NN] = sh[255];
}

__global__ void rowptr_kernel(const int* __restrict__ cnt, const int* __restrict__ blockoff,
                              int* __restrict__ row_ptr) {
  __shared__ int sh[256];
  int t = threadIdx.x;
  int idx = blockIdx.x * 256 + t;
  int v = idx < NN ? cnt[idx] : 0;
  sh[t] = v;
  __syncthreads();
  for (int off = 1; off < 256; off <<= 1) {
    int u = (t >= off) ? sh[t - off] : 0;
    __syncthreads();
    sh[t] += u;
    __syncthreads();
  }
  if (idx < NN) row_ptr[idx] = blockoff[blockIdx.x] + sh[t] - v;
}

// ---- degree-sorted node permutation (two-level counting sort, 256 bins) ----
// LDS-local histograms kill same-address global atomic chains: global chain depth
// per bin drops from ~4000 (one per node in the hot bin -> 106us serialized) to
// NBLK=157 (one per block). Scheduling-only permutation: per-node math and output
// rows unchanged -> output deterministic regardless of atomic ordering.
__global__ void dhist_kernel(const int* __restrict__ cnt, int* __restrict__ dbin) {
  __shared__ int lbin[256];
  int t = threadIdx.x;
  lbin[t] = 0;
  __syncthreads();
  int n = blockIdx.x * 256 + t;
  if (n < NN) {
    int d = cnt[n];
    if (d > 255) d = 255;
    atomicAdd(&lbin[d], 1);
  }
  __syncthreads();
  if (lbin[t]) atomicAdd(&dbin[t], lbin[t]);
}

__global__ void dscan_kernel(const int* __restrict__ dbin, int* __restrict__ doff) {
  __shared__ int sh[256];
  int t = threadIdx.x;
  int v = dbin[t];
  sh[t] = v;
  __syncthreads();
  for (int off = 1; off < 256; off <<= 1) {
    int u = (t >= off) ? sh[t - off] : 0;
    __syncthreads();
    sh[t] += u;
    __syncthreads();
  }
  doff[t] = sh[t] - v;  // exclusive
}

__global__ void dperm_kernel(const int* __restrict__ cnt, const int* __restrict__ doff,
                             int* __restrict__ dfill, int* __restrict__ perm) {
  __shared__ int lbin[256];
  __shared__ int lbase[256];
  int t = threadIdx.x;
  lbin[t] = 0;
  __syncthreads();
  int n = blockIdx.x * 256 + t;
  int d = 0, lrank = 0;
  if (n < NN) {
    d = cnt[n];
    if (d > 255) d = 255;
    lrank = atomicAdd(&lbin[d], 1);  // LDS atomic: local rank within (block, bin)
  }
  __syncthreads();
  if (lbin[t]) lbase[t] = atomicAdd(&dfill[t], lbin[t]);  // one global atomic per (block, bin)
  __syncthreads();
  if (n < NN) perm[doff[d] + lbase[d] + lrank] = n;
}

// pure read + ONE 8B store per edge (no atomic: rank precomputed in hist).
__global__ void scatter_kernel(const int* __restrict__ src, const int* __restrict__ dst,
                               const float* __restrict__ dist,
                               const int* __restrict__ row_ptr, const int* __restrict__ rank,
                               int2* __restrict__ csr_ew) {
  int e = blockIdx.x * blockDim.x + threadIdx.x;
  if (e >= NE) return;
  int pos = row_ptr[dst[e]] + rank[e];
  float dd = dist[e] + 1e-6f;
  float w = 1.0f / (dd * dd);
  csr_ew[pos] = make_int2(src[e], (int)__float_as_uint(w));
}

__global__ void wsum_kernel(const int* __restrict__ row_ptr, const int2* __restrict__ csr_ew,
                            float* __restrict__ wsum) {
  int n = blockIdx.x * blockDim.x + threadIdx.x;
  if (n >= NN) return;
  int s = row_ptr[n], e = row_ptr[n + 1];
  float acc = 0.f;
  for (int i = s; i < e; ++i) acc += __uint_as_float((unsigned)csr_ew[i].y);
  wsum[n] = acc;
}

// -------- fused per-layer: wave-per-node gather -> LDS -> MFMA linear -> hout --------
// Block = 16 waves = 16 degree-sorted nodes (perm) -> all waves have ~equal edge
// counts -> minimal __syncthreads imbalance. Phase 1: each wave runs the 4-edge/
// VMEM gather for ITS node, writes bf16 hi/lo row to LDS. One barrier. Phase 2:
// waves 0-7 each compute one 16x16 output tile from the shared LDS A-tile via
// split-bf16 MFMA (a*w ~= ah*wh + ah*wl + al*wh, fp32 acc), store to natural rows.
// D-layout: col(kout)=lane&15, row(slot)=(lane>>4)*4+reg [guide §3, m89-verified].
// hin/hout double-buffered (blocks read random hin rows while others write hout).
__global__ void __launch_bounds__(1024) fused_layer_kernel(
    const __half* __restrict__ hin, const int* __restrict__ row_ptr,
    const int2* __restrict__ csr_ew, const int* __restrict__ perm,
    const unsigned short* __restrict__ whi, const unsigned short* __restrict__ wlo,
    const float* __restrict__ wsum, const float* __restrict__ b,
    __half* __restrict__ hout) {
  __shared__ __align__(16) unsigned short sAh[16][LSTRIDE];
  __shared__ __align__(16) unsigned short sAl[16][LSTRIDE];
  int wave = threadIdx.x >> 6;
  int lane = threadIdx.x & 63;
  int wid = __builtin_amdgcn_readfirstlane(perm[blockIdx.x * 16 + wave]);  // this wave's node

  // ---- phase 1: aggregate this wave's node (4 edges per VMEM instr) ----
  {
    int s = __builtin_amdgcn_readfirstlane(row_ptr[wid]);
    int e = __builtin_amdgcn_readfirstlane(row_ptr[wid + 1]);
    int g = lane >> 4;   // edge slot within a quad
    int k = lane & 15;   // col octet: cols [8k, 8k+8)
    const __half* hp = hin + k * 8;
    float a[8] = {0.f, 0.f, 0.f, 0.f, 0.f, 0.f, 0.f, 0.f};
    int i = s;
    for (; i + 16 <= e; i += 16) {  // clamp-free main strips
      uint4 hv[4];
      float wv[4];
#pragma unroll
      for (int u = 0; u < 4; ++u) {
        int2 p = csr_ew[i + u * 4 + g];
        wv[u] = __uint_as_float((unsigned)p.y);
        hv[u] = *reinterpret_cast<const uint4*>(hp + (size_t)p.x * HID);
      }
#pragma unroll
      for (int u = 0; u < 4; ++u) {
        const __half2* q = reinterpret_cast<const __half2*>(&hv[u]);
#pragma unroll
        for (int c = 0; c < 4; ++c) {
          float2 f = __half22float2(q[c]);
          a[2 * c] += wv[u] * f.x;
          a[2 * c + 1] += wv[u] * f.y;
        }
      }
    }
    for (; i < e; i += 4) {  // tail quads (clamped, w=0 pads vanish exactly)
      int j = i + g;
      int jc = j < e ? j : e - 1;
      int2 p = csr_ew[jc];
      float w = (j < e) ? __uint_as_float((unsigned)p.y) : 0.f;
      uint4 hv = *reinterpret_cast<const uint4*>(hp + (size_t)p.x * HID);
      const __half2* q = reinterpret_cast<const __half2*>(&hv);
#pragma unroll
      for (int c = 0; c < 4; ++c) {
        float2 f = __half22float2(q[c]);
        a[2 * c] += w * f.x;
        a[2 * c + 1] += w * f.y;
      }
    }
#pragma unroll
    for (int c = 0; c < 8; ++c) {
      a[c] += __shfl_xor(a[c], 16, 64);
      a[c] += __shfl_xor(a[c], 32, 64);
    }
    if (g == 0) {
      unsigned short hh[8], ll[8];
#pragma unroll
      for (int c = 0; c < 8; ++c) {
        hh[c] = f32_to_bf16_rne(a[c]);
        ll[c] = f32_to_bf16_rne(a[c] - bf16_to_f32(hh[c]));
      }
      *reinterpret_cast<uint4*>(&sAh[wave][k * 8]) = *reinterpret_cast<const uint4*>(hh);
      *reinterpret_cast<uint4*>(&sAl[wave][k * 8]) = *reinterpret_cast<const uint4*>(ll);
    }
  }
  __syncthreads();

  // ---- phase 2: waves 0-7 each compute one 16x16 output tile ----
  if (wave >= 8) return;
  int t = wave;
  int mrow = lane & 15;
  int kc = (lane >> 4) * 8;

  f32x4 acc = (f32x4){0.f, 0.f, 0.f, 0.f};
#pragma unroll
  for (int si = 0; si < 4; ++si) {
    int joff = si * 32 + kc;
    bf16x8 ah = *reinterpret_cast<const bf16x8*>(&sAh[mrow][joff]);
    bf16x8 al = *reinterpret_cast<const bf16x8*>(&sAl[mrow][joff]);
    bf16x8 bh = *reinterpret_cast<const bf16x8*>(whi + (t * 16 + mrow) * HID + joff);
    bf16x8 bl = *reinterpret_cast<const bf16x8*>(wlo + (t * 16 + mrow) * HID + joff);
    acc = __builtin_amdgcn_mfma_f32_16x16x32_bf16(ah, bh, acc, 0, 0, 0);
    acc = __builtin_amdgcn_mfma_f32_16x16x32_bf16(ah, bl, acc, 0, 0, 0);
    acc = __builtin_amdgcn_mfma_f32_16x16x32_bf16(al, bh, acc, 0, 0, 0);
  }

  int slotBase = (lane >> 4) * 4;
  int kout = t * 16 + mrow;
  float bk = b[kout];
#pragma unroll
  for (int r = 0; r < 4; ++r) {
    int node = perm[blockIdx.x * 16 + slotBase + r];
    float v = acc[r] + bk * wsum[node];
    hout[(size_t)node * HID + kout] = __float2half(fmaxf(v, 0.f));
  }
}

// ---------------- cluster softmax head (wave per node) ----------------
__global__ void cluster_kernel(const __half* __restrict__ h, const float* __restrict__ cW,
                               const float* __restrict__ cb, float* __restrict__ out) {
  int wid = (blockIdx.x * blockDim.x + threadIdx.x) >> 6;
  int lane = threadIdx.x & 63;
  if (wid >= NN) return;
  float h0 = __half2float(h[wid * HID + lane]);
  float h1 = __half2float(h[wid * HID + 64 + lane]);
  float logit[3];
#pragma unroll
  for (int c = 0; c < 3; ++c) {
    float p = h0 * cW[c * HID + lane] + h1 * cW[c * HID + 64 + lane];
#pragma unroll
    for (int off = 32; off > 0; off >>= 1) p += __shfl_xor(p, off, 64);
    logit[c] = p + cb[c];
  }
  if (lane == 0) {
    float m = fmaxf(logit[0], fmaxf(logit[1], logit[2]));
    float e0 = expf(logit[0] - m), e1 = expf(logit[1] - m), e2 = expf(logit[2] - m);
    float inv = 1.0f / (e0 + e1 + e2);
    out[wid * 3 + 0] = e0 * inv;
    out[wid * 3 + 1] = e1 * inv;
    out[wid * 3 + 2] = e2 * inv;
  }
}

// ---------------- energy head: two-stage column reduction ----------------
__global__ void colsum_part_kernel(const __half* __restrict__ h, float* __restrict__ partial) {
  int t = threadIdx.x;
  int col = t & 127;
  int lane_id = blockIdx.x * 2 + (t >> 7);  // [0, 2048)
  float acc = 0.f;
  for (int r = lane_id; r < NN; r += 2048) acc += __half2float(h[r * HID + col]);
  partial[lane_id * HID + col] = acc;
}

__global__ void energy_final_kernel(const float* __restrict__ partial,
                                    const float* __restrict__ eW, const float* __restrict__ eb,
                                    float* __restrict__ out) {
  __shared__ float sh[8][HID];
  __shared__ float red[2];
  int t = threadIdx.x;
  int col = t & 127;
  int slot = t >> 7;  // 0..7
  float acc = 0.f;
  for (int i = 0; i < 256; ++i) acc += partial[(slot + 8 * i) * HID + col];
  sh[slot][col] = acc;
  __syncthreads();
  if (t < 128) {
    float s = 0.f;
#pragma unroll
    for (int j = 0; j < 8; ++j) s += sh[j][t];
    float v = s * (1.0f / NN) * eW[t];
#pragma unroll
    for (int off = 32; off > 0; off >>= 1) v += __shfl_xor(v, off, 64);
    if ((t & 63) == 0) red[t >> 6] = v;
  }
  __syncthreads();
  if (t == 0) {
    float e = red[0] + red[1] + eb[0];
    out[NN * 3] = e;
    out[NN * 3 + 1] = (e < -1.0f) ? 1.0f : 0.0f;
  }
}

extern "C" void kernel_launch(void* const* d_in, const int* in_sizes, int n_in,
                              void* d_out, int out_size, void* d_ws, size_t ws_size,
                              hipStream_t stream) {
  const float* x    = (const float*)d_in[0];
  const int*   ei   = (const int*)d_in[1];
  const float* dist = (const float*)d_in[2];
  const float* encW = (const float*)d_in[3];
  const float* encb = (const float*)d_in[4];
  const float* convW = (const float*)d_in[5];
  const float* convb = (const float*)d_in[6];
  const float* cW   = (const float*)d_in[7];
  const float* cb   = (const float*)d_in[8];
  const float* eW   = (const float*)d_in[9];
  const float* eb   = (const float*)d_in[10];
  float* out = (float*)d_out;

  // workspace layout (bytes)
  char* ws = (char*)d_ws;
  __half*         h1      = (__half*)        (ws + 0);           // 10,240,000
  __half*         h2      = (__half*)        (ws + 10240000);    // 10,240,000 (dbuf)
  char*           scratch = (char*)          (ws + 20480000);    // 10,240,000 (scan+bins+colsum)
  int2*           csr_ew  = (int2*)          (ws + 30720000);    //  5,120,000
  int*            row_ptr = (int*)           (ws + 35840000);    //    160,064
  int*            cnt     = (int*)           (ws + 36000064);    //    160,000
  float*          wsum    = (float*)         (ws + 36160064);    //    160,000
  unsigned short* whi5    = (unsigned short*)(ws + 36320064);    //    163,840
  unsigned short* wlo5    = (unsigned short*)(ws + 36483904);    //    163,840
  int*            rank    = (int*)           (ws + 36647744);    //  2,560,000
  int*            perm    = (int*)           (ws + 39207744);    //    160,000
  if (ws_size < (size_t)39367744) return;  // insufficient scratch — fail visibly

  int*   blocksum = (int*)scratch;            // 157 ints
  int*   blockoff = (int*)scratch + 512;      // 157 ints
  int*   dbin     = (int*)scratch + 1024;     // 256 ints
  int*   dfill    = (int*)scratch + 1280;     // 256 ints
  int*   doff     = (int*)scratch + 1536;     // 256 ints
  float* partial  = (float*)scratch;          // 1 MB (used after CSR build)

  const int* srcI = ei;
  const int* dstI = ei + NE;

  hipMemsetAsync(cnt, 0, 160000, stream);
  hipMemsetAsync(dbin, 0, 2048, stream);  // dbin + dfill (contiguous)

  encoder_wconv_kernel<<<20320, 256, 0, stream>>>(x, encW, encb, h1, convW, whi5, wlo5);

  hist_kernel<<<(NE + 255) / 256, 256, 0, stream>>>(dstI, cnt, rank);
  partial_kernel<<<NBLK, 256, 0, stream>>>(cnt, blocksum);
  scan_small_kernel<<<1, 256, 0, stream>>>(blocksum, blockoff, row_ptr);
  rowptr_kernel<<<NBLK, 256, 0, stream>>>(cnt, blockoff, row_ptr);
  dhist_kernel<<<NBLK, 256, 0, stream>>>(cnt, dbin);
  dscan_kernel<<<1, 256, 0, stream>>>(dbin, doff);
  dperm_kernel<<<NBLK, 256, 0, stream>>>(cnt, doff, dfill, perm);
  scatter_kernel<<<(NE + 255) / 256, 256, 0, stream>>>(srcI, dstI, dist, row_ptr, rank, csr_ew);
  wsum_kernel<<<(NN + 255) / 256, 256, 0, stream>>>(row_ptr, csr_ew, wsum);

  __half* hin = h1;
  __half* hout = h2;
  for (int l = 0; l < NL; ++l) {
    fused_layer_kernel<<<NN / 16, 1024, 0, stream>>>(hin, row_ptr, csr_ew, perm,
                                                     whi5 + (size_t)l * HID * HID,
                                                     wlo5 + (size_t)l * HID * HID,
                                                     wsum, convb + (size_t)l * HID, hout);
    __half* tmp = hin; hin = hout; hout = tmp;
  }
  // after 5 layers, final h is in hin

  cluster_kernel<<<(NN * 64 + 255) / 256, 256, 0, stream>>>(hin, cW, cb, out);
  colsum_part_kernel<<<1024, 256, 0, stream>>>(hin, partial);
  energy_final_kernel<<<1, 1024, 0, stream>>>(partial, eW, eb, out);
}

// Round 18
// 329.745 us; speedup vs baseline: 1.6715x; 1.0463x over previous
//
#include <hip/hip_runtime.h>
#include <hip/hip_fp16.h>

#define NN 40000
#define NE 640000
#define HID 128
#define NL 5
#define NBLK 157  // ceil(40000/256)
#define LSTRIDE 136  // 128 + 8 pad shorts -> 272B rows; 2-way bank aliasing only (free)

typedef __attribute__((ext_vector_type(8))) short bf16x8;
typedef __attribute__((ext_vector_type(4))) float f32x4;

static __device__ __forceinline__ unsigned short f32_to_bf16_rne(float f) {
  unsigned int u = __float_as_uint(f);
  unsigned int lsb = (u >> 16) & 1u;
  u += 0x7fffu + lsb;
  return (unsigned short)(u >> 16);
}
static __device__ __forceinline__ float bf16_to_f32(unsigned short s) {
  return __uint_as_float(((unsigned int)s) << 16);
}

// ---- fused: encoder (blocks 0..19999) + conv_W bf16 hi/lo split (blocks 20000+) ----
__global__ void encoder_wconv_kernel(const float* __restrict__ x, const float* __restrict__ encW,
                                     const float* __restrict__ encb, __half* __restrict__ h,
                                     const float* __restrict__ convW,
                                     unsigned short* __restrict__ whi,
                                     unsigned short* __restrict__ wlo) {
  int b = blockIdx.x;
  if (b < 20000) {
    int gid = b * 256 + threadIdx.x;  // < NN*HID
    int n = gid >> 7, k = gid & 127;
    const float* xp = x + n * 7;
    const float* wp = encW + k * 7;
    float acc = encb[k];
#pragma unroll
    for (int i = 0; i < 7; ++i) acc += xp[i] * wp[i];
    h[gid] = __float2half(acc);
  } else {
    int i = (b - 20000) * 256 + threadIdx.x;
    if (i < NL * HID * HID) {
      float w = convW[i];
      unsigned short hi = f32_to_bf16_rne(w);
      unsigned short lo = f32_to_bf16_rne(w - bf16_to_f32(hi));
      whi[i] = hi;
      wlo[i] = lo;
    }
  }
}

// ---------------- CSR build ----------------
__global__ void hist_kernel(const int* __restrict__ dst, int* __restrict__ cnt,
                            int* __restrict__ rank) {
  int e = blockIdx.x * blockDim.x + threadIdx.x;
  if (e < NE) rank[e] = atomicAdd(&cnt[dst[e]], 1);
}

__global__ void partial_kernel(const int* __restrict__ cnt, int* __restrict__ blocksum) {
  __shared__ int red[4];
  int t = threadIdx.x;
  int idx = blockIdx.x * 256 + t;
  int v = idx < NN ? cnt[idx] : 0;
#pragma unroll
  for (int off = 32; off > 0; off >>= 1) v += __shfl_xor(v, off, 64);
  if ((t & 63) == 0) red[t >> 6] = v;
  __syncthreads();
  if (t == 0) blocksum[blockIdx.x] = red[0] + red[1] + red[2] + red[3];
}

__global__ void scan_small_kernel(const int* __restrict__ blocksum, int* __restrict__ blockoff,
                                  int* __restrict__ row_ptr) {
  __shared__ int sh[256];
  int t = threadIdx.x;
  int v = t < NBLK ? blocksum[t] : 0;
  sh[t] = v;
  __syncthreads();
  for (int off = 1; off < 256; off <<= 1) {
    int u = (t >= off) ? sh[t - off] : 0;
    __syncthreads();
    sh[t] += u;
    __syncthreads();
  }
  if (t < NBLK) blockoff[t] = sh[t] - v;
  if (t == 255) row_ptr[NN] = sh[255];
}

__global__ void rowptr_kernel(const int* __restrict__ cnt, const int* __restrict__ blockoff,
                              int* __restrict__ row_ptr) {
  __shared__ int sh[256];
  int t = threadIdx.x;
  int idx = blockIdx.x * 256 + t;
  int v = idx < NN ? cnt[idx] : 0;
  sh[t] = v;
  __syncthreads();
  for (int off = 1; off < 256; off <<= 1) {
    int u = (t >= off) ? sh[t - off] : 0;
    __syncthreads();
    sh[t] += u;
    __syncthreads();
  }
  if (idx < NN) row_ptr[idx] = blockoff[blockIdx.x] + sh[t] - v;
}

// pure read + ONE 8B store per edge (no atomic: rank precomputed in hist).
__global__ void scatter_kernel(const int* __restrict__ src, const int* __restrict__ dst,
                               const float* __restrict__ dist,
                               const int* __restrict__ row_ptr, const int* __restrict__ rank,
                               int2* __restrict__ csr_ew) {
  int e = blockIdx.x * blockDim.x + threadIdx.x;
  if (e >= NE) return;
  int pos = row_ptr[dst[e]] + rank[e];
  float dd = dist[e] + 1e-6f;
  float w = 1.0f / (dd * dd);
  csr_ew[pos] = make_int2(src[e], (int)__float_as_uint(w));
}

__global__ void wsum_kernel(const int* __restrict__ row_ptr, const int2* __restrict__ csr_ew,
                            float* __restrict__ wsum) {
  int n = blockIdx.x * blockDim.x + threadIdx.x;
  if (n >= NN) return;
  int s = row_ptr[n], e = row_ptr[n + 1];
  float acc = 0.f;
  for (int i = s; i < e; ++i) acc += __uint_as_float((unsigned)csr_ew[i].y);
  wsum[n] = acc;
}

// -------- fused per-layer: gather (2 nodes/wave) -> LDS -> MFMA linear -> hout --------
// Block = 16 waves x 2 nodes = 32 nodes. vs R15's 16-node blocks: (a) halves the
// per-layer W L2 traffic (1250 blocks x 64KB = 80MB, was 160MB), (b) barrier
// imbalance drops (max/mean of Poisson(32) sums over 16 waves ~1.45x vs 1.68x),
// (c) phase 2 uses ALL 16 waves (2 row-blocks x 8 kout-blocks = 16 tiles).
// Resident-wave TLP unchanged: 2 blocks/CU x 16 waves = 32 waves/CU either way.
// Phase 2 via split-bf16 MFMA (a*w ~= ah*wh + ah*wl + al*wh, fp32 acc).
// D-layout: col(kout)=lane&15, row(slot)=(lane>>4)*4+reg [guide §3, m89-verified].
// hin/hout double-buffered (blocks read random hin rows while others write hout).
__global__ void __launch_bounds__(1024) fused_layer_kernel(
    const __half* __restrict__ hin, const int* __restrict__ row_ptr,
    const int2* __restrict__ csr_ew,
    const unsigned short* __restrict__ whi, const unsigned short* __restrict__ wlo,
    const float* __restrict__ wsum, const float* __restrict__ b,
    __half* __restrict__ hout) {
  __shared__ __align__(16) unsigned short sAh[32][LSTRIDE];
  __shared__ __align__(16) unsigned short sAl[32][LSTRIDE];
  int wave = threadIdx.x >> 6;
  int lane = threadIdx.x & 63;
  int node0 = blockIdx.x * 32;

  // ---- phase 1: gather-aggregate 2 nodes (4 edges per VMEM instr each) ----
  int g = lane >> 4;   // edge slot within a quad
  int k = lane & 15;   // col octet: cols [8k, 8k+8)
  const __half* hp = hin + k * 8;
#pragma unroll
  for (int t = 0; t < 2; ++t) {
    int slot = wave * 2 + t;
    int wid = node0 + slot;
    int s = __builtin_amdgcn_readfirstlane(row_ptr[wid]);
    int e = __builtin_amdgcn_readfirstlane(row_ptr[wid + 1]);
    float a[8] = {0.f, 0.f, 0.f, 0.f, 0.f, 0.f, 0.f, 0.f};
    int i = s;
    for (; i + 16 <= e; i += 16) {  // clamp-free main strips
      uint4 hv[4];
      float wv[4];
#pragma unroll
      for (int u = 0; u < 4; ++u) {
        int2 p = csr_ew[i + u * 4 + g];
        wv[u] = __uint_as_float((unsigned)p.y);
        hv[u] = *reinterpret_cast<const uint4*>(hp + (size_t)p.x * HID);
      }
#pragma unroll
      for (int u = 0; u < 4; ++u) {
        const __half2* q = reinterpret_cast<const __half2*>(&hv[u]);
#pragma unroll
        for (int c = 0; c < 4; ++c) {
          float2 f = __half22float2(q[c]);
          a[2 * c] += wv[u] * f.x;
          a[2 * c + 1] += wv[u] * f.y;
        }
      }
    }
    for (; i < e; i += 4) {  // tail quads (clamped, w=0 pads vanish exactly)
      int j = i + g;
      int jc = j < e ? j : e - 1;
      int2 p = csr_ew[jc];
      float w = (j < e) ? __uint_as_float((unsigned)p.y) : 0.f;
      uint4 hv = *reinterpret_cast<const uint4*>(hp + (size_t)p.x * HID);
      const __half2* q = reinterpret_cast<const __half2*>(&hv);
#pragma unroll
      for (int c = 0; c < 4; ++c) {
        float2 f = __half22float2(q[c]);
        a[2 * c] += w * f.x;
        a[2 * c + 1] += w * f.y;
      }
    }
#pragma unroll
    for (int c = 0; c < 8; ++c) {
      a[c] += __shfl_xor(a[c], 16, 64);
      a[c] += __shfl_xor(a[c], 32, 64);
    }
    if (g == 0) {
      unsigned short hh[8], ll[8];
#pragma unroll
      for (int c = 0; c < 8; ++c) {
        hh[c] = f32_to_bf16_rne(a[c]);
        ll[c] = f32_to_bf16_rne(a[c] - bf16_to_f32(hh[c]));
      }
      *reinterpret_cast<uint4*>(&sAh[slot][k * 8]) = *reinterpret_cast<const uint4*>(hh);
      *reinterpret_cast<uint4*>(&sAl[slot][k * 8]) = *reinterpret_cast<const uint4*>(ll);
    }
  }
  __syncthreads();

  // ---- phase 2: 16 waves x 16 tiles (2 row-blocks x 8 kout-blocks) ----
  int rowblk = wave >> 3;  // 0..1
  int kblk = wave & 7;     // 0..7
  int mrow = lane & 15;
  int kc = (lane >> 4) * 8;

  f32x4 acc = (f32x4){0.f, 0.f, 0.f, 0.f};
#pragma unroll
  for (int si = 0; si < 4; ++si) {
    int joff = si * 32 + kc;
    bf16x8 ah = *reinterpret_cast<const bf16x8*>(&sAh[rowblk * 16 + mrow][joff]);
    bf16x8 al = *reinterpret_cast<const bf16x8*>(&sAl[rowblk * 16 + mrow][joff]);
    bf16x8 bh = *reinterpret_cast<const bf16x8*>(whi + (kblk * 16 + mrow) * HID + joff);
    bf16x8 bl = *reinterpret_cast<const bf16x8*>(wlo + (kblk * 16 + mrow) * HID + joff);
    acc = __builtin_amdgcn_mfma_f32_16x16x32_bf16(ah, bh, acc, 0, 0, 0);
    acc = __builtin_amdgcn_mfma_f32_16x16x32_bf16(ah, bl, acc, 0, 0, 0);
    acc = __builtin_amdgcn_mfma_f32_16x16x32_bf16(al, bh, acc, 0, 0, 0);
  }

  int slotBase = rowblk * 16 + (lane >> 4) * 4;
  int kout = kblk * 16 + mrow;
  float bk = b[kout];
#pragma unroll
  for (int r = 0; r < 4; ++r) {
    int node = node0 + slotBase + r;
    float v = acc[r] + bk * wsum[node];
    hout[(size_t)node * HID + kout] = __float2half(fmaxf(v, 0.f));
  }
}

// ---------------- cluster softmax head (wave per node) ----------------
__global__ void cluster_kernel(const __half* __restrict__ h, const float* __restrict__ cW,
                               const float* __restrict__ cb, float* __restrict__ out) {
  int wid = (blockIdx.x * blockDim.x + threadIdx.x) >> 6;
  int lane = threadIdx.x & 63;
  if (wid >= NN) return;
  float h0 = __half2float(h[wid * HID + lane]);
  float h1 = __half2float(h[wid * HID + 64 + lane]);
  float logit[3];
#pragma unroll
  for (int c = 0; c < 3; ++c) {
    float p = h0 * cW[c * HID + lane] + h1 * cW[c * HID + 64 + lane];
#pragma unroll
    for (int off = 32; off > 0; off >>= 1) p += __shfl_xor(p, off, 64);
    logit[c] = p + cb[c];
  }
  if (lane == 0) {
    float m = fmaxf(logit[0], fmaxf(logit[1], logit[2]));
    float e0 = expf(logit[0] - m), e1 = expf(logit[1] - m), e2 = expf(logit[2] - m);
    float inv = 1.0f / (e0 + e1 + e2);
    out[wid * 3 + 0] = e0 * inv;
    out[wid * 3 + 1] = e1 * inv;
    out[wid * 3 + 2] = e2 * inv;
  }
}

// ---------------- energy head: two-stage column reduction ----------------
__global__ void colsum_part_kernel(const __half* __restrict__ h, float* __restrict__ partial) {
  int t = threadIdx.x;
  int col = t & 127;
  int lane_id = blockIdx.x * 2 + (t >> 7);  // [0, 2048)
  float acc = 0.f;
  for (int r = lane_id; r < NN; r += 2048) acc += __half2float(h[r * HID + col]);
  partial[lane_id * HID + col] = acc;
}

__global__ void energy_final_kernel(const float* __restrict__ partial,
                                    const float* __restrict__ eW, const float* __restrict__ eb,
                                    float* __restrict__ out) {
  __shared__ float sh[8][HID];
  __shared__ float red[2];
  int t = threadIdx.x;
  int col = t & 127;
  int slot = t >> 7;  // 0..7
  float acc = 0.f;
  for (int i = 0; i < 256; ++i) acc += partial[(slot + 8 * i) * HID + col];
  sh[slot][col] = acc;
  __syncthreads();
  if (t < 128) {
    float s = 0.f;
#pragma unroll
    for (int j = 0; j < 8; ++j) s += sh[j][t];
    float v = s * (1.0f / NN) * eW[t];
#pragma unroll
    for (int off = 32; off > 0; off >>= 1) v += __shfl_xor(v, off, 64);
    if ((t & 63) == 0) red[t >> 6] = v;
  }
  __syncthreads();
  if (t == 0) {
    float e = red[0] + red[1] + eb[0];
    out[NN * 3] = e;
    out[NN * 3 + 1] = (e < -1.0f) ? 1.0f : 0.0f;
  }
}

extern "C" void kernel_launch(void* const* d_in, const int* in_sizes, int n_in,
                              void* d_out, int out_size, void* d_ws, size_t ws_size,
                              hipStream_t stream) {
  const float* x    = (const float*)d_in[0];
  const int*   ei   = (const int*)d_in[1];
  const float* dist = (const float*)d_in[2];
  const float* encW = (const float*)d_in[3];
  const float* encb = (const float*)d_in[4];
  const float* convW = (const float*)d_in[5];
  const float* convb = (const float*)d_in[6];
  const float* cW   = (const float*)d_in[7];
  const float* cb   = (const float*)d_in[8];
  const float* eW   = (const float*)d_in[9];
  const float* eb   = (const float*)d_in[10];
  float* out = (float*)d_out;

  // workspace layout (bytes)
  char* ws = (char*)d_ws;
  __half*         h1      = (__half*)        (ws + 0);           // 10,240,000
  __half*         h2      = (__half*)        (ws + 10240000);    // 10,240,000 (dbuf)
  char*           scratch = (char*)          (ws + 20480000);    // 10,240,000 (scan+colsum)
  int2*           csr_ew  = (int2*)          (ws + 30720000);    //  5,120,000
  int*            row_ptr = (int*)           (ws + 35840000);    //    160,064
  int*            cnt     = (int*)           (ws + 36000064);    //    160,000
  float*          wsum    = (float*)         (ws + 36160064);    //    160,000
  unsigned short* whi5    = (unsigned short*)(ws + 36320064);    //    163,840
  unsigned short* wlo5    = (unsigned short*)(ws + 36483904);    //    163,840
  int*            rank    = (int*)           (ws + 36647744);    //  2,560,000
  if (ws_size < (size_t)39207744) return;  // insufficient scratch — fail visibly

  int*   blocksum = (int*)scratch;
  int*   blockoff = (int*)scratch + 512;
  float* partial  = (float*)scratch;  // 1 MB (used after CSR build)

  const int* srcI = ei;
  const int* dstI = ei + NE;

  hipMemsetAsync(cnt, 0, 160000, stream);

  encoder_wconv_kernel<<<20320, 256, 0, stream>>>(x, encW, encb, h1, convW, whi5, wlo5);

  hist_kernel<<<(NE + 255) / 256, 256, 0, stream>>>(dstI, cnt, rank);
  partial_kernel<<<NBLK, 256, 0, stream>>>(cnt, blocksum);
  scan_small_kernel<<<1, 256, 0, stream>>>(blocksum, blockoff, row_ptr);
  rowptr_kernel<<<NBLK, 256, 0, stream>>>(cnt, blockoff, row_ptr);
  scatter_kernel<<<(NE + 255) / 256, 256, 0, stream>>>(srcI, dstI, dist, row_ptr, rank, csr_ew);
  wsum_kernel<<<(NN + 255) / 256, 256, 0, stream>>>(row_ptr, csr_ew, wsum);

  __half* hin = h1;
  __half* hout = h2;
  for (int l = 0; l < NL; ++l) {
    fused_layer_kernel<<<NN / 32, 1024, 0, stream>>>(hin, row_ptr, csr_ew,
                                                     whi5 + (size_t)l * HID * HID,
                                                     wlo5 + (size_t)l * HID * HID,
                                                     wsum, convb + (size_t)l * HID, hout);
    __half* tmp = hin; hin = hout; hout = tmp;
  }
  // after 5 layers, final h is in hin

  cluster_kernel<<<(NN * 64 + 255) / 256, 256, 0, stream>>>(hin, cW, cb, out);
  colsum_part_kernel<<<1024, 256, 0, stream>>>(hin, partial);
  energy_final_kernel<<<1, 1024, 0, stream>>>(partial, eW, eb, out);
}